// Round 1
// baseline (140.241 us; speedup 1.0000x reference)
//
#include <hip/hip_runtime.h>

#define HH 512
#define WW 512
#define NB HH   // one block per row

// ---------------------------------------------------------------------------
// Persistent device-global sync state. Module-load initializes to 0; the
// barrier is sense-reversing (g_cnt returns to 0 after each use, g_gen grows
// monotonically) and the finalize ticket self-resets, so every graph replay
// sees a clean state without any workspace init kernel.
// ---------------------------------------------------------------------------
__device__ unsigned int g_cnt    = 0;
__device__ unsigned int g_gen    = 0;
__device__ unsigned int g_ticket = 0;

__device__ __forceinline__ void grid_sync() {
    __syncthreads();                       // block's global stores drained (vmcnt 0)
    if (threadIdx.x == 0) {
        __threadfence();                   // release: write back this XCD's L2
        unsigned int gen = __hip_atomic_load(&g_gen, __ATOMIC_RELAXED,
                                             __HIP_MEMORY_SCOPE_AGENT);
        unsigned int old = __hip_atomic_fetch_add(&g_cnt, 1u, __ATOMIC_ACQ_REL,
                                                  __HIP_MEMORY_SCOPE_AGENT);
        if (old == NB - 1u) {
            __hip_atomic_store(&g_cnt, 0u, __ATOMIC_RELAXED,
                               __HIP_MEMORY_SCOPE_AGENT);
            __hip_atomic_fetch_add(&g_gen, 1u, __ATOMIC_RELEASE,
                                   __HIP_MEMORY_SCOPE_AGENT);
        } else {
            while (__hip_atomic_load(&g_gen, __ATOMIC_RELAXED,
                                     __HIP_MEMORY_SCOPE_AGENT) == gen) {
                __builtin_amdgcn_s_sleep(1);
            }
        }
        __threadfence();                   // acquire: invalidate L1/L2 for fresh reads
    }
    __syncthreads();
}

// ---------------------------------------------------------------------------
// Fused kernel: phase A computes the combined surface mask (bit0=pred surface,
// bit1=gt surface) for this block's row; a grid barrier makes mAB globally
// visible; phase B is the exact EDT + masked reduction + ticket finalize of
// the previous 2-kernel version (identical fp32 arithmetic -> absmax 0).
// __launch_bounds__(512,4): VGPR<=128 -> 2 blocks/CU -> all 512 blocks
// co-resident (required by grid_sync, guaranteed by cooperative launch).
// ---------------------------------------------------------------------------
__global__ __launch_bounds__(512, 4) void fused_kernel(
        const float* __restrict__ pred, const float* __restrict__ gt,
        unsigned char* __restrict__ mAB, double* __restrict__ partials,
        float* __restrict__ out) {
    __shared__ float  srow[2][3][WW];
    __shared__ float2 s2[WW];
    __shared__ double lred[16];
    __shared__ int    winner;
    const int r = blockIdx.x;
    const int c = threadIdx.x;

    // ---- Phase A: surface = center && !(up && dn && lf && rt), OOB = false ----
    srow[0][1][c] = pred[r * WW + c];
    srow[1][1][c] = gt[r * WW + c];
    srow[0][0][c] = (r > 0)      ? pred[(r - 1) * WW + c] : 0.0f;
    srow[1][0][c] = (r > 0)      ? gt[(r - 1) * WW + c]   : 0.0f;
    srow[0][2][c] = (r < HH - 1) ? pred[(r + 1) * WW + c] : 0.0f;
    srow[1][2][c] = (r < HH - 1) ? gt[(r + 1) * WW + c]   : 0.0f;
    __syncthreads();
    unsigned int bits = 0u;
    #pragma unroll
    for (int f = 0; f < 2; ++f) {
        bool ctr = srow[f][1][c] != 0.0f;
        bool up  = srow[f][0][c] != 0.0f;
        bool dn  = srow[f][2][c] != 0.0f;
        bool lf  = (c > 0)      && (srow[f][1][c - 1] != 0.0f);
        bool rt  = (c < WW - 1) && (srow[f][1][c + 1] != 0.0f);
        if (ctr && !(up && dn && lf && rt)) bits |= (1u << f);
    }
    mAB[r * WW + c] = (unsigned char)bits;

    grid_sync();   // all surface rows globally visible

    // ---- Phase B: vertical nearest-feature distance, batched probes ----
    bool fa = (bits & 1u) != 0u;
    bool fb = (bits & 2u) != 0u;
    int foundA = fa ? 0 : -1;
    int foundB = fb ? 0 : -1;
    for (int kb = 1; kb < HH && (foundA < 0 || foundB < 0); kb += 4) {
        unsigned int mu[4], md[4];
        #pragma unroll
        for (int i = 0; i < 4; ++i) {
            int ku = kb + i;
            int ru = r - ku, rd = r + ku;
            mu[i] = (ru >= 0) ? (unsigned int)mAB[ru * WW + c] : 0u;
            md[i] = (rd < HH) ? (unsigned int)mAB[rd * WW + c] : 0u;
        }
        #pragma unroll
        for (int i = 0; i < 4; ++i) {
            unsigned int hit = mu[i] | md[i];
            if (foundA < 0 && (hit & 1u)) foundA = kb + i;
            if (foundB < 0 && (hit & 2u)) foundB = kb + i;
        }
    }
    float sent = 1e6f + (float)((r + 1 < HH - r) ? (r + 1) : (HH - r));
    float ga = (foundA >= 0) ? (float)foundA : sent;
    float gb = (foundB >= 0) ? (float)foundB : sent;
    s2[c] = make_float2(ga * ga, gb * gb);
    __syncthreads();

    // ---- horizontal min-plus, batched with exact early exit ----
    float2 o2 = s2[c];
    float besta = o2.x, bestb = o2.y;
    for (int kb = 1; kb < WW; kb += 4) {
        float kk2 = (float)(kb * kb);
        if (kk2 >= besta && kk2 >= bestb) break;
        #pragma unroll
        for (int i = 0; i < 4; ++i) {
            int k = kb + i;
            float k2 = (float)(k * k);
            int cl = c - k, cr = c + k;
            if (cl >= 0) {
                float2 g = s2[cl];
                besta = fminf(besta, g.x + k2);
                bestb = fminf(bestb, g.y + k2);
            }
            if (cr < WW) {
                float2 g = s2[cr];
                besta = fminf(besta, g.x + k2);
                bestb = fminf(bestb, g.y + k2);
            }
        }
    }

    // ---- masked reduction: num = sum(dta*spm) + sum(dtb*sm) ----
    float wA = fa ? 1.0f : 0.0f;
    float wB = fb ? 1.0f : 0.0f;
    double lnum = (double)(sqrtf(besta) * wB + sqrtf(bestb) * wA);
    double lden = (double)(wA + wB);
    for (int off = 32; off > 0; off >>= 1) {
        lnum += __shfl_down(lnum, off, 64);
        lden += __shfl_down(lden, off, 64);
    }
    int wv = c >> 6;
    if ((c & 63) == 0) { lred[wv] = lnum; lred[8 + wv] = lden; }
    __syncthreads();
    if (c == 0) {
        double n = 0.0, d = 0.0;
        #pragma unroll
        for (int i = 0; i < 8; ++i) { n += lred[i]; d += lred[8 + i]; }
        partials[2 * r]     = n;
        partials[2 * r + 1] = d;
        __threadfence();                       // release partials
        unsigned int old = __hip_atomic_fetch_add(&g_ticket, 1u, __ATOMIC_ACQ_REL,
                                                  __HIP_MEMORY_SCOPE_AGENT);
        winner = (old == NB - 1u) ? 1 : 0;
    }
    __syncthreads();

    // ---- last block finalizes: parallel sum of 512 row partials ----
    if (winner) {
        __threadfence();                       // acquire all partials
        double n = partials[2 * c];
        double d = partials[2 * c + 1];
        for (int off = 32; off > 0; off >>= 1) {
            n += __shfl_down(n, off, 64);
            d += __shfl_down(d, off, 64);
        }
        if ((c & 63) == 0) { lred[c >> 6] = n; lred[8 + (c >> 6)] = d; }
        __syncthreads();
        if (c == 0) {
            double nn = 0.0, dd = 0.0;
            #pragma unroll
            for (int i = 0; i < 8; ++i) { nn += lred[i]; dd += lred[8 + i]; }
            out[0] = (float)(nn / dd);
            // self-reset ticket for the next graph replay
            __hip_atomic_store(&g_ticket, 0u, __ATOMIC_RELAXED,
                               __HIP_MEMORY_SCOPE_AGENT);
        }
    }
}

extern "C" void kernel_launch(void* const* d_in, const int* in_sizes, int n_in,
                              void* d_out, int out_size, void* d_ws, size_t ws_size,
                              hipStream_t stream) {
    const float* pred = (const float*)d_in[0];
    const float* gt   = (const float*)d_in[1];
    float* out = (float*)d_out;

    char* ws = (char*)d_ws;
    double* partials   = (double*)ws;                 // 8 KB
    unsigned char* mAB = (unsigned char*)(ws + 8192); // 256 KB

    void* args[] = { (void*)&pred, (void*)&gt, (void*)&mAB,
                     (void*)&partials, (void*)&out };
    hipLaunchCooperativeKernel((const void*)fused_kernel, dim3(NB), dim3(WW),
                               args, 0, stream);
}

// Round 2
// 95.235 us; speedup vs baseline: 1.4726x; 1.4726x over previous
//
#include <hip/hip_runtime.h>

#define HH 512
#define WW 512
#define NB HH   // one block per row

// ---------------------------------------------------------------------------
// Persistent device-global sync state (module-load zero-init, self-resetting
// across graph replays: g_cnt returns to 0 each barrier, g_gen is monotonic,
// g_ticket resets in the winner block).
//
// ALL cross-block communication (mAB, partials, sync vars) goes through
// relaxed AGENT-scope atomics: these compile to sc0/sc1 cache-bypassing
// loads/stores coherent at the memory-side point, with ZERO buffer_wbl2 /
// buffer_inv cache-maintenance ops. Round-1 showed 4 full-L2 fences per
// block x 512 blocks = ~70us of serialized L2 flush/inv; this removes them.
// Ordering is provided by instruction completion: __syncthreads() drains
// vmcnt(0) for all waves' stores, plus two explicit s_waitcnt vmcnt(0).
// ---------------------------------------------------------------------------
__device__ unsigned int g_cnt    = 0;
__device__ unsigned int g_gen    = 0;
__device__ unsigned int g_ticket = 0;

#define AT_LD(p)    __hip_atomic_load((p),      __ATOMIC_RELAXED, __HIP_MEMORY_SCOPE_AGENT)
#define AT_ST(p, v) __hip_atomic_store((p), (v), __ATOMIC_RELAXED, __HIP_MEMORY_SCOPE_AGENT)
#define AT_ADD(p)   __hip_atomic_fetch_add((p), 1u, __ATOMIC_RELAXED, __HIP_MEMORY_SCOPE_AGENT)

__global__ __launch_bounds__(512, 4) void fused_kernel(
        const float* __restrict__ pred, const float* __restrict__ gt,
        unsigned int* __restrict__ mAB, double* __restrict__ partials,
        float* __restrict__ out) {
    __shared__ float  srow[2][3][WW];
    __shared__ float2 s2[WW];
    __shared__ double lred[16];
    __shared__ int    winner;
    const int r = blockIdx.x;
    const int c = threadIdx.x;

    // ---- Phase A: surface = center && !(up && dn && lf && rt), OOB = false ----
    srow[0][1][c] = pred[r * WW + c];
    srow[1][1][c] = gt[r * WW + c];
    srow[0][0][c] = (r > 0)      ? pred[(r - 1) * WW + c] : 0.0f;
    srow[1][0][c] = (r > 0)      ? gt[(r - 1) * WW + c]   : 0.0f;
    srow[0][2][c] = (r < HH - 1) ? pred[(r + 1) * WW + c] : 0.0f;
    srow[1][2][c] = (r < HH - 1) ? gt[(r + 1) * WW + c]   : 0.0f;
    __syncthreads();
    unsigned int bits = 0u;
    #pragma unroll
    for (int f = 0; f < 2; ++f) {
        bool ctr = srow[f][1][c] != 0.0f;
        bool up  = srow[f][0][c] != 0.0f;
        bool dn  = srow[f][2][c] != 0.0f;
        bool lf  = (c > 0)      && (srow[f][1][c - 1] != 0.0f);
        bool rt  = (c < WW - 1) && (srow[f][1][c + 1] != 0.0f);
        if (ctr && !(up && dn && lf && rt)) bits |= (1u << f);
    }
    AT_ST(&mAB[r * WW + c], bits);           // coherent, cache-bypassing store

    // ---- grid barrier: no fences, no cache maintenance ----
    __syncthreads();                          // drains vmcnt(0): mAB stores done
    if (c == 0) {
        unsigned int gen = AT_LD(&g_gen);
        // order the gen snapshot before the arrival RMW (else a late-returning
        // snapshot could capture the post-release value -> deadlock)
        asm volatile("s_waitcnt vmcnt(0) lgkmcnt(0)" ::: "memory");
        unsigned int old = AT_ADD(&g_cnt);
        if (old == NB - 1u) {
            AT_ST(&g_cnt, 0u);
            AT_ADD(&g_gen);                   // release the barrier
        } else {
            while (AT_LD(&g_gen) == gen) { __builtin_amdgcn_s_sleep(2); }
        }
    }
    __syncthreads();

    // ---- Phase B: vertical nearest-feature distance, batched probes ----
    bool fa = (bits & 1u) != 0u;
    bool fb = (bits & 2u) != 0u;
    int foundA = fa ? 0 : -1;
    int foundB = fb ? 0 : -1;
    for (int kb = 1; kb < HH && (foundA < 0 || foundB < 0); kb += 4) {
        unsigned int mu[4], md[4];
        #pragma unroll
        for (int i = 0; i < 4; ++i) {
            int ku = kb + i;
            int ru = r - ku, rd = r + ku;
            mu[i] = (ru >= 0) ? AT_LD(&mAB[ru * WW + c]) : 0u;
            md[i] = (rd < HH) ? AT_LD(&mAB[rd * WW + c]) : 0u;
        }
        #pragma unroll
        for (int i = 0; i < 4; ++i) {
            unsigned int hit = mu[i] | md[i];
            if (foundA < 0 && (hit & 1u)) foundA = kb + i;
            if (foundB < 0 && (hit & 2u)) foundB = kb + i;
        }
    }
    float sent = 1e6f + (float)((r + 1 < HH - r) ? (r + 1) : (HH - r));
    float ga = (foundA >= 0) ? (float)foundA : sent;
    float gb = (foundB >= 0) ? (float)foundB : sent;
    s2[c] = make_float2(ga * ga, gb * gb);
    __syncthreads();

    // ---- horizontal min-plus, batched with exact early exit ----
    float2 o2 = s2[c];
    float besta = o2.x, bestb = o2.y;
    for (int kb = 1; kb < WW; kb += 4) {
        float kk2 = (float)(kb * kb);
        if (kk2 >= besta && kk2 >= bestb) break;
        #pragma unroll
        for (int i = 0; i < 4; ++i) {
            int k = kb + i;
            float k2 = (float)(k * k);
            int cl = c - k, cr = c + k;
            if (cl >= 0) {
                float2 g = s2[cl];
                besta = fminf(besta, g.x + k2);
                bestb = fminf(bestb, g.y + k2);
            }
            if (cr < WW) {
                float2 g = s2[cr];
                besta = fminf(besta, g.x + k2);
                bestb = fminf(bestb, g.y + k2);
            }
        }
    }

    // ---- masked reduction: num = sum(dta*spm) + sum(dtb*sm) ----
    float wA = fa ? 1.0f : 0.0f;
    float wB = fb ? 1.0f : 0.0f;
    double lnum = (double)(sqrtf(besta) * wB + sqrtf(bestb) * wA);
    double lden = (double)(wA + wB);
    for (int off = 32; off > 0; off >>= 1) {
        lnum += __shfl_down(lnum, off, 64);
        lden += __shfl_down(lden, off, 64);
    }
    int wv = c >> 6;
    if ((c & 63) == 0) { lred[wv] = lnum; lred[8 + wv] = lden; }
    __syncthreads();
    if (c == 0) {
        double n = 0.0, d = 0.0;
        #pragma unroll
        for (int i = 0; i < 8; ++i) { n += lred[i]; d += lred[8 + i]; }
        AT_ST(&partials[2 * r],     n);       // coherent stores
        AT_ST(&partials[2 * r + 1], d);
        // partials must be complete before the ticket increment is visible
        asm volatile("s_waitcnt vmcnt(0) lgkmcnt(0)" ::: "memory");
        unsigned int old = AT_ADD(&g_ticket);
        winner = (old == NB - 1u) ? 1 : 0;
    }
    __syncthreads();

    // ---- last block finalizes: parallel sum of 512 row partials ----
    if (winner) {
        double n = AT_LD(&partials[2 * c]);   // coherent loads
        double d = AT_LD(&partials[2 * c + 1]);
        for (int off = 32; off > 0; off >>= 1) {
            n += __shfl_down(n, off, 64);
            d += __shfl_down(d, off, 64);
        }
        if ((c & 63) == 0) { lred[c >> 6] = n; lred[8 + (c >> 6)] = d; }
        __syncthreads();
        if (c == 0) {
            double nn = 0.0, dd = 0.0;
            #pragma unroll
            for (int i = 0; i < 8; ++i) { nn += lred[i]; dd += lred[8 + i]; }
            out[0] = (float)(nn / dd);
            AT_ST(&g_ticket, 0u);             // self-reset for next replay
        }
    }
}

extern "C" void kernel_launch(void* const* d_in, const int* in_sizes, int n_in,
                              void* d_out, int out_size, void* d_ws, size_t ws_size,
                              hipStream_t stream) {
    const float* pred = (const float*)d_in[0];
    const float* gt   = (const float*)d_in[1];
    float* out = (float*)d_out;

    char* ws = (char*)d_ws;
    double* partials  = (double*)ws;                  // 8 KB
    unsigned int* mAB = (unsigned int*)(ws + 8192);   // 1 MB (uint per pixel)

    void* args[] = { (void*)&pred, (void*)&gt, (void*)&mAB,
                     (void*)&partials, (void*)&out };
    hipLaunchCooperativeKernel((const void*)fused_kernel, dim3(NB), dim3(WW),
                               args, 0, stream);
}

// Round 3
// 79.388 us; speedup vs baseline: 1.7665x; 1.1996x over previous
//
#include <hip/hip_runtime.h>

#define HH 512
#define WW 512
#define NB HH   // one block per row

// ---------------------------------------------------------------------------
// Single regular kernel, NO grid barrier, NO cooperative launch.
//
// Key structural change vs rounds 1-2: the vertical EDT probe recomputes the
// surface bit of any probed pixel ON THE FLY from pred/gt (center + 4-neighbor
// erosion test). pred/gt are read-only kernel inputs -> plain cached loads,
// L1-resident per block (a row is 2 KB, probes re-read the same few rows).
// This removes the only producer->consumer dependency that forced a grid
// barrier (round 1: 73us of fence stall; round 2: ~30us of barrier polling
// congestion on a single memory-side cacheline).
//
// Cross-block machinery left: row partials + ticket finalize (proven in
// round 0 at 72us total). Ordering: each block's thread 0 stores partials
// with cache-bypassing agent-scope stores, s_waitcnt vmcnt(0), then bumps
// the ticket; the last block therefore sees all partials via bypassing loads.
// g_ticket is module-load zero-init and self-reset by the winner each replay.
// ---------------------------------------------------------------------------
__device__ unsigned int g_ticket = 0;

#define AT_LD(p)    __hip_atomic_load((p),       __ATOMIC_RELAXED, __HIP_MEMORY_SCOPE_AGENT)
#define AT_ST(p, v) __hip_atomic_store((p), (v), __ATOMIC_RELAXED, __HIP_MEMORY_SCOPE_AGENT)
#define AT_ADD(p)   __hip_atomic_fetch_add((p), 1u, __ATOMIC_RELAXED, __HIP_MEMORY_SCOPE_AGENT)

// surface bits (bit0 = pred, bit1 = gt) for pixel (ru, c), 0 <= ru < HH.
// S = center && !(up && dn && lf && rt), OOB neighbor = false.
// 10 predicated coalesced loads; caches do the dedup across threads/steps.
__device__ __forceinline__ unsigned int surf2(const float* __restrict__ pa,
                                              const float* __restrict__ pb,
                                              int ru, int c) {
    const int base = ru * WW + c;
    float a_c = pa[base];
    float b_c = pb[base];
    float a_u = (ru > 0)      ? pa[base - WW] : 0.0f;
    float b_u = (ru > 0)      ? pb[base - WW] : 0.0f;
    float a_d = (ru < HH - 1) ? pa[base + WW] : 0.0f;
    float b_d = (ru < HH - 1) ? pb[base + WW] : 0.0f;
    float a_l = (c > 0)       ? pa[base - 1]  : 0.0f;
    float b_l = (c > 0)       ? pb[base - 1]  : 0.0f;
    float a_r = (c < WW - 1)  ? pa[base + 1]  : 0.0f;
    float b_r = (c < WW - 1)  ? pb[base + 1]  : 0.0f;
    unsigned int bits = 0u;
    if (a_c != 0.0f && !(a_u != 0.0f && a_d != 0.0f && a_l != 0.0f && a_r != 0.0f)) bits |= 1u;
    if (b_c != 0.0f && !(b_u != 0.0f && b_d != 0.0f && b_l != 0.0f && b_r != 0.0f)) bits |= 2u;
    return bits;
}

__global__ __launch_bounds__(512) void fused_kernel(
        const float* __restrict__ pred, const float* __restrict__ gt,
        double* __restrict__ partials, float* __restrict__ out) {
    __shared__ float2 s2[WW];
    __shared__ double lred[16];
    __shared__ int    winner;
    const int r = blockIdx.x;
    const int c = threadIdx.x;

    // ---- vertical nearest-surface distance, surface bits computed on the fly
    unsigned int own = surf2(pred, gt, r, c);
    bool fa = (own & 1u) != 0u;
    bool fb = (own & 2u) != 0u;
    int foundA = fa ? 0 : -1;
    int foundB = fb ? 0 : -1;
    for (int k = 1; k < HH && (foundA < 0 || foundB < 0); ++k) {
        int ru = r - k, rd = r + k;
        if (ru < 0 && rd >= HH) break;        // column exhausted (empty column)
        unsigned int hit = 0u;
        if (ru >= 0) hit |= surf2(pred, gt, ru, c);
        if (rd < HH) hit |= surf2(pred, gt, rd, c);
        if (foundA < 0 && (hit & 1u)) foundA = k;
        if (foundB < 0 && (hit & 2u)) foundB = k;
    }
    float sent = 1e6f + (float)((r + 1 < HH - r) ? (r + 1) : (HH - r));
    float ga = (foundA >= 0) ? (float)foundA : sent;
    float gb = (foundB >= 0) ? (float)foundB : sent;
    s2[c] = make_float2(ga * ga, gb * gb);
    __syncthreads();

    // ---- horizontal min-plus, batched with exact early exit ----
    float2 o2 = s2[c];
    float besta = o2.x, bestb = o2.y;
    for (int kb = 1; kb < WW; kb += 4) {
        float kk2 = (float)(kb * kb);
        if (kk2 >= besta && kk2 >= bestb) break;
        #pragma unroll
        for (int i = 0; i < 4; ++i) {
            int k = kb + i;
            float k2 = (float)(k * k);
            int cl = c - k, cr = c + k;
            if (cl >= 0) {
                float2 g = s2[cl];
                besta = fminf(besta, g.x + k2);
                bestb = fminf(bestb, g.y + k2);
            }
            if (cr < WW) {
                float2 g = s2[cr];
                besta = fminf(besta, g.x + k2);
                bestb = fminf(bestb, g.y + k2);
            }
        }
    }

    // ---- masked reduction: num = sum(dta*spm) + sum(dtb*sm) ----
    float wA = fa ? 1.0f : 0.0f;
    float wB = fb ? 1.0f : 0.0f;
    double lnum = (double)(sqrtf(besta) * wB + sqrtf(bestb) * wA);
    double lden = (double)(wA + wB);
    for (int off = 32; off > 0; off >>= 1) {
        lnum += __shfl_down(lnum, off, 64);
        lden += __shfl_down(lden, off, 64);
    }
    int wv = c >> 6;
    if ((c & 63) == 0) { lred[wv] = lnum; lred[8 + wv] = lden; }
    __syncthreads();
    if (c == 0) {
        double n = 0.0, d = 0.0;
        #pragma unroll
        for (int i = 0; i < 8; ++i) { n += lred[i]; d += lred[8 + i]; }
        AT_ST(&partials[2 * r],     n);       // cache-bypassing coherent stores
        AT_ST(&partials[2 * r + 1], d);
        // partials must be globally visible before our ticket increment
        asm volatile("s_waitcnt vmcnt(0) lgkmcnt(0)" ::: "memory");
        unsigned int old = AT_ADD(&g_ticket);
        winner = (old == NB - 1u) ? 1 : 0;
    }
    __syncthreads();

    // ---- last block finalizes: parallel sum of 512 row partials ----
    if (winner) {
        double n = AT_LD(&partials[2 * c]);
        double d = AT_LD(&partials[2 * c + 1]);
        for (int off = 32; off > 0; off >>= 1) {
            n += __shfl_down(n, off, 64);
            d += __shfl_down(d, off, 64);
        }
        if ((c & 63) == 0) { lred[c >> 6] = n; lred[8 + (c >> 6)] = d; }
        __syncthreads();
        if (c == 0) {
            double nn = 0.0, dd = 0.0;
            #pragma unroll
            for (int i = 0; i < 8; ++i) { nn += lred[i]; dd += lred[8 + i]; }
            out[0] = (float)(nn / dd);
            AT_ST(&g_ticket, 0u);             // self-reset for next replay
        }
    }
}

extern "C" void kernel_launch(void* const* d_in, const int* in_sizes, int n_in,
                              void* d_out, int out_size, void* d_ws, size_t ws_size,
                              hipStream_t stream) {
    const float* pred = (const float*)d_in[0];
    const float* gt   = (const float*)d_in[1];
    float* out = (float*)d_out;

    double* partials = (double*)d_ws;         // 8 KB, fully overwritten each run

    fused_kernel<<<dim3(NB), dim3(WW), 0, stream>>>(pred, gt, partials, out);
}

// Round 4
// 70.814 us; speedup vs baseline: 1.9804x; 1.1211x over previous
//
#include <hip/hip_runtime.h>

#define HH 512
#define WW 512
#define NB HH   // one block per row

// ---------------------------------------------------------------------------
// Single regular kernel, no grid barrier, no cooperative launch.
//
// Vertical EDT probe uses TWO 3-row sliding windows of mask bits in LDS
// (up / down direction rings). At step k every thread loads ONE new row per
// direction per mask (4 coalesced global loads), stores the 2-bit mask word
// into the ring, and the surface test for rows r-k / r+k is computed from LDS
// bitwise on the packed bits: surf = ctr & ~(up & dn & lf & rt). This replaces
// round-3's 20-load-per-step serial surf2 chain (kernel ~14us) with a
// ~8-step window walk (~2us): same values, same fp32 math -> absmax 0.
//
// Exit is block-wide via __syncthreads_and (expected depth ~8 for ~47% dense
// surfaces); the same barrier doubles as the read/overwrite fence for the
// ring slots (slot (k+1)%3 was last READ at step k-1, written at step k).
//
// Cross-block machinery: row partials + ticket finalize (proven R0/R3).
// Thread 0 stores partials with agent-scope cache-bypassing stores, waits
// vmcnt(0), then bumps the ticket; last block reduces all 512 partials.
// g_ticket is module-load zero-init and self-reset by the winner each replay.
// ---------------------------------------------------------------------------
__device__ unsigned int g_ticket = 0;

#define AT_LD(p)    __hip_atomic_load((p),       __ATOMIC_RELAXED, __HIP_MEMORY_SCOPE_AGENT)
#define AT_ST(p, v) __hip_atomic_store((p), (v), __ATOMIC_RELAXED, __HIP_MEMORY_SCOPE_AGENT)
#define AT_ADD(p)   __hip_atomic_fetch_add((p), 1u, __ATOMIC_RELAXED, __HIP_MEMORY_SCOPE_AGENT)

__global__ __launch_bounds__(512) void fused_kernel(
        const float* __restrict__ pred, const float* __restrict__ gt,
        double* __restrict__ partials, float* __restrict__ out) {
    __shared__ unsigned int uR[3][WW + 2];   // mask bits of row r-j at slot j%3
    __shared__ unsigned int dR[3][WW + 2];   // mask bits of row r+j at slot j%3
    __shared__ float2 s2[WW];
    __shared__ double lred[16];
    __shared__ int    winner;
    const int r = blockIdx.x;
    const int c = threadIdx.x;

    // zero the left/right pads (columns 0 and WW+1 are never written again)
    if (c < 6) {
        int s = c >> 1;
        int p = (c & 1) ? (WW + 1) : 0;
        uR[s][p] = 0u;
        dR[s][p] = 0u;
    }

    // mask bits (bit0 = pred, bit1 = gt) for (row, c); OOB row -> 0
    auto mbits = [&](int row) -> unsigned int {
        unsigned int b = 0u;
        if (row >= 0 && row < HH) {
            if (pred[row * WW + c] != 0.0f) b |= 1u;
            if (gt[row * WW + c]   != 0.0f) b |= 2u;
        }
        return b;
    };

    // init rings: U{slot0=row r, slot1=row r-1}, D{slot0=row r, slot1=row r+1}
    unsigned int b0 = mbits(r);
    uR[0][c + 1] = b0;
    dR[0][c + 1] = b0;
    uR[1][c + 1] = mbits(r - 1);
    dR[1][c + 1] = mbits(r + 1);
    __syncthreads();

    // own surface bits (k = 0): border OOB neighbors are 0 in the rings
    unsigned int own = uR[0][c + 1] &
        ~(uR[1][c + 1] & dR[1][c + 1] & uR[0][c] & uR[0][c + 2]);
    bool fa = (own & 1u) != 0u;
    bool fb = (own & 2u) != 0u;
    int foundA = fa ? 0 : -1;
    int foundB = fb ? 0 : -1;
    bool done = (foundA >= 0) && (foundB >= 0);

    // ---- vertical probe: sliding-window walk, block-wide early exit ----
    for (int k = 1; k < HH; ++k) {
        if (__syncthreads_and((int)done)) break;   // also fences ring reuse
        const int sl = (k + 1) % 3;                // slot for rows r-(k+1)/r+(k+1)
        uR[sl][c + 1] = mbits(r - k - 1);
        dR[sl][c + 1] = mbits(r + k + 1);
        __syncthreads();                           // new rows visible
        unsigned int hit = 0u;
        const int km = k % 3, kp = (k - 1 + 3) % 3;
        if (r - k >= 0) {                          // surface of row r-k
            hit |= uR[km][c + 1] &
                ~(uR[sl][c + 1] & uR[kp][c + 1] & uR[km][c] & uR[km][c + 2]);
        }
        if (r + k < HH) {                          // surface of row r+k
            hit |= dR[km][c + 1] &
                ~(dR[sl][c + 1] & dR[kp][c + 1] & dR[km][c] & dR[km][c + 2]);
        }
        if (foundA < 0 && (hit & 1u)) foundA = k;
        if (foundB < 0 && (hit & 2u)) foundB = k;
        done = (foundA >= 0) && (foundB >= 0);
    }

    float sent = 1e6f + (float)((r + 1 < HH - r) ? (r + 1) : (HH - r));
    float ga = (foundA >= 0) ? (float)foundA : sent;
    float gb = (foundB >= 0) ? (float)foundB : sent;
    s2[c] = make_float2(ga * ga, gb * gb);
    __syncthreads();

    // ---- horizontal min-plus, batched with exact early exit ----
    float2 o2 = s2[c];
    float besta = o2.x, bestb = o2.y;
    for (int kb = 1; kb < WW; kb += 4) {
        float kk2 = (float)(kb * kb);
        if (kk2 >= besta && kk2 >= bestb) break;
        #pragma unroll
        for (int i = 0; i < 4; ++i) {
            int k = kb + i;
            float k2 = (float)(k * k);
            int cl = c - k, cr = c + k;
            if (cl >= 0) {
                float2 g = s2[cl];
                besta = fminf(besta, g.x + k2);
                bestb = fminf(bestb, g.y + k2);
            }
            if (cr < WW) {
                float2 g = s2[cr];
                besta = fminf(besta, g.x + k2);
                bestb = fminf(bestb, g.y + k2);
            }
        }
    }

    // ---- masked reduction: num = sum(dta*spm) + sum(dtb*sm) ----
    float wA = fa ? 1.0f : 0.0f;
    float wB = fb ? 1.0f : 0.0f;
    double lnum = (double)(sqrtf(besta) * wB + sqrtf(bestb) * wA);
    double lden = (double)(wA + wB);
    for (int off = 32; off > 0; off >>= 1) {
        lnum += __shfl_down(lnum, off, 64);
        lden += __shfl_down(lden, off, 64);
    }
    int wv = c >> 6;
    if ((c & 63) == 0) { lred[wv] = lnum; lred[8 + wv] = lden; }
    __syncthreads();
    if (c == 0) {
        double n = 0.0, d = 0.0;
        #pragma unroll
        for (int i = 0; i < 8; ++i) { n += lred[i]; d += lred[8 + i]; }
        AT_ST(&partials[2 * r],     n);       // cache-bypassing coherent stores
        AT_ST(&partials[2 * r + 1], d);
        // partials must be globally visible before our ticket increment
        asm volatile("s_waitcnt vmcnt(0) lgkmcnt(0)" ::: "memory");
        unsigned int old = AT_ADD(&g_ticket);
        winner = (old == NB - 1u) ? 1 : 0;
    }
    __syncthreads();

    // ---- last block finalizes: parallel sum of 512 row partials ----
    if (winner) {
        double n = AT_LD(&partials[2 * c]);
        double d = AT_LD(&partials[2 * c + 1]);
        for (int off = 32; off > 0; off >>= 1) {
            n += __shfl_down(n, off, 64);
            d += __shfl_down(d, off, 64);
        }
        if ((c & 63) == 0) { lred[c >> 6] = n; lred[8 + (c >> 6)] = d; }
        __syncthreads();
        if (c == 0) {
            double nn = 0.0, dd = 0.0;
            #pragma unroll
            for (int i = 0; i < 8; ++i) { nn += lred[i]; dd += lred[8 + i]; }
            out[0] = (float)(nn / dd);
            AT_ST(&g_ticket, 0u);             // self-reset for next replay
        }
    }
}

extern "C" void kernel_launch(void* const* d_in, const int* in_sizes, int n_in,
                              void* d_out, int out_size, void* d_ws, size_t ws_size,
                              hipStream_t stream) {
    const float* pred = (const float*)d_in[0];
    const float* gt   = (const float*)d_in[1];
    float* out = (float*)d_out;

    double* partials = (double*)d_ws;         // 8 KB, fully overwritten each run

    fused_kernel<<<dim3(NB), dim3(WW), 0, stream>>>(pred, gt, partials, out);
}

// Round 5
// 69.771 us; speedup vs baseline: 2.0100x; 1.0150x over previous
//
#include <hip/hip_runtime.h>

#define HH 512
#define WW 512
#define NB HH   // one block per row

// ---------------------------------------------------------------------------
// Single regular kernel, no grid barrier, no cooperative launch.
//
// Vertical EDT probe: two 6-slot sliding windows (up/down) of 2-bit mask
// words in LDS, walked in BATCHES of 4 rows. A batch testing k in [kb,kb+3]
// needs row-offsets j in [kb-1, kb+4] -- exactly 6 consecutive j, so slot =
// j % 6 is collision-free. Per batch: 16 independent global loads issued
// together (4 rows x 2 dirs x {pred,gt}), one ds_write pass, ONE
// __syncthreads, then 4 k-steps tested from LDS. The __syncthreads_and
// early-exit check doubles as the slot-reuse fence (slots overwritten in
// batch kb were last read in batch kb-4). vs round-4's 1-row steps this cuts
// block barriers ~18 -> ~6 and exposes load latency ~3x instead of ~9x.
// Surface test is bitwise on packed bits: surf = ctr & ~(up&dn&lf&rt).
// Same search order, same fp32 ops as rounds 0-4 -> absmax 0.
//
// Cross-block machinery: row partials + ticket finalize (proven R0/R3/R4).
// Thread 0 stores partials with agent-scope cache-bypassing stores, waits
// vmcnt(0), then bumps the ticket; last block reduces all 512 partials.
// g_ticket is module-load zero-init and self-reset by the winner each replay.
// ---------------------------------------------------------------------------
__device__ unsigned int g_ticket = 0;

#define AT_LD(p)    __hip_atomic_load((p),       __ATOMIC_RELAXED, __HIP_MEMORY_SCOPE_AGENT)
#define AT_ST(p, v) __hip_atomic_store((p), (v), __ATOMIC_RELAXED, __HIP_MEMORY_SCOPE_AGENT)
#define AT_ADD(p)   __hip_atomic_fetch_add((p), 1u, __ATOMIC_RELAXED, __HIP_MEMORY_SCOPE_AGENT)

__global__ __launch_bounds__(512) void fused_kernel(
        const float* __restrict__ pred, const float* __restrict__ gt,
        double* __restrict__ partials, float* __restrict__ out) {
    __shared__ unsigned int uR[6][WW + 2];   // row r-j at slot j%6
    __shared__ unsigned int dR[6][WW + 2];   // row r+j at slot j%6
    __shared__ float2 s2[WW];
    __shared__ double lred[16];
    __shared__ int    winner;
    const int r = blockIdx.x;
    const int c = threadIdx.x;

    // zero the left/right pads of all 6 slots (never written again)
    if (c < 12) {
        int s = c >> 1;
        int p = (c & 1) ? (WW + 1) : 0;
        uR[s][p] = 0u;
        dR[s][p] = 0u;
    }

    // mask bits (bit0 = pred, bit1 = gt) for (row, c); OOB row -> 0
    auto mbits = [&](int row) -> unsigned int {
        unsigned int b = 0u;
        if (row >= 0 && row < HH) {
            if (pred[row * WW + c] != 0.0f) b |= 1u;
            if (gt[row * WW + c]   != 0.0f) b |= 2u;
        }
        return b;
    };

    // init: j=0 (row r) and j=1 (rows r-1 / r+1)
    unsigned int b0 = mbits(r);
    uR[0][c + 1] = b0;
    dR[0][c + 1] = b0;
    uR[1][c + 1] = mbits(r - 1);
    dR[1][c + 1] = mbits(r + 1);
    __syncthreads();

    // own surface bits (k = 0): OOB neighbors are 0 in the rings
    unsigned int own = uR[0][c + 1] &
        ~(uR[1][c + 1] & dR[1][c + 1] & uR[0][c] & uR[0][c + 2]);
    bool fa = (own & 1u) != 0u;
    bool fb = (own & 2u) != 0u;
    int foundA = fa ? 0 : -1;
    int foundB = fb ? 0 : -1;
    bool done = (foundA >= 0) && (foundB >= 0);

    // ---- vertical probe: 4-row batches, block-wide early exit ----
    for (int kb = 1; kb < HH; kb += 4) {
        if (__syncthreads_and((int)done)) break;   // also fences slot reuse
        // issue all 16 loads (rows j = kb+1 .. kb+4, both directions)
        unsigned int wu[4], wd[4];
        #pragma unroll
        for (int i = 0; i < 4; ++i) {
            wu[i] = mbits(r - (kb + 1 + i));
            wd[i] = mbits(r + (kb + 1 + i));
        }
        #pragma unroll
        for (int i = 0; i < 4; ++i) {
            int sl = (kb + 1 + i) % 6;
            uR[sl][c + 1] = wu[i];
            dR[sl][c + 1] = wd[i];
        }
        __syncthreads();                           // new rows visible
        #pragma unroll
        for (int i = 0; i < 4; ++i) {
            int k = kb + i;
            int km = k % 6, kp = (k - 1) % 6, kn = (k + 1) % 6;
            unsigned int hit = 0u;
            if (r - k >= 0) {                      // surface of row r-k
                hit |= uR[km][c + 1] &
                    ~(uR[kn][c + 1] & uR[kp][c + 1] & uR[km][c] & uR[km][c + 2]);
            }
            if (r + k < HH) {                      // surface of row r+k
                hit |= dR[km][c + 1] &
                    ~(dR[kn][c + 1] & dR[kp][c + 1] & dR[km][c] & dR[km][c + 2]);
            }
            if (foundA < 0 && (hit & 1u)) foundA = k;
            if (foundB < 0 && (hit & 2u)) foundB = k;
        }
        done = (foundA >= 0) && (foundB >= 0);
    }

    float sent = 1e6f + (float)((r + 1 < HH - r) ? (r + 1) : (HH - r));
    float ga = (foundA >= 0) ? (float)foundA : sent;
    float gb = (foundB >= 0) ? (float)foundB : sent;
    s2[c] = make_float2(ga * ga, gb * gb);
    __syncthreads();

    // ---- horizontal min-plus, batched with exact early exit ----
    float2 o2 = s2[c];
    float besta = o2.x, bestb = o2.y;
    for (int kb = 1; kb < WW; kb += 4) {
        float kk2 = (float)(kb * kb);
        if (kk2 >= besta && kk2 >= bestb) break;
        #pragma unroll
        for (int i = 0; i < 4; ++i) {
            int k = kb + i;
            float k2 = (float)(k * k);
            int cl = c - k, cr = c + k;
            if (cl >= 0) {
                float2 g = s2[cl];
                besta = fminf(besta, g.x + k2);
                bestb = fminf(bestb, g.y + k2);
            }
            if (cr < WW) {
                float2 g = s2[cr];
                besta = fminf(besta, g.x + k2);
                bestb = fminf(bestb, g.y + k2);
            }
        }
    }

    // ---- masked reduction: num = sum(dta*spm) + sum(dtb*sm) ----
    float wA = fa ? 1.0f : 0.0f;
    float wB = fb ? 1.0f : 0.0f;
    double lnum = (double)(sqrtf(besta) * wB + sqrtf(bestb) * wA);
    double lden = (double)(wA + wB);
    for (int off = 32; off > 0; off >>= 1) {
        lnum += __shfl_down(lnum, off, 64);
        lden += __shfl_down(lden, off, 64);
    }
    int wv = c >> 6;
    if ((c & 63) == 0) { lred[wv] = lnum; lred[8 + wv] = lden; }
    __syncthreads();
    if (c == 0) {
        double n = 0.0, d = 0.0;
        #pragma unroll
        for (int i = 0; i < 8; ++i) { n += lred[i]; d += lred[8 + i]; }
        AT_ST(&partials[2 * r],     n);       // cache-bypassing coherent stores
        AT_ST(&partials[2 * r + 1], d);
        // partials must be globally visible before our ticket increment
        asm volatile("s_waitcnt vmcnt(0) lgkmcnt(0)" ::: "memory");
        unsigned int old = AT_ADD(&g_ticket);
        winner = (old == NB - 1u) ? 1 : 0;
    }
    __syncthreads();

    // ---- last block finalizes: parallel sum of 512 row partials ----
    if (winner) {
        double n = AT_LD(&partials[2 * c]);
        double d = AT_LD(&partials[2 * c + 1]);
        for (int off = 32; off > 0; off >>= 1) {
            n += __shfl_down(n, off, 64);
            d += __shfl_down(d, off, 64);
        }
        if ((c & 63) == 0) { lred[c >> 6] = n; lred[8 + (c >> 6)] = d; }
        __syncthreads();
        if (c == 0) {
            double nn = 0.0, dd = 0.0;
            #pragma unroll
            for (int i = 0; i < 8; ++i) { nn += lred[i]; dd += lred[8 + i]; }
            out[0] = (float)(nn / dd);
            AT_ST(&g_ticket, 0u);             // self-reset for next replay
        }
    }
}

extern "C" void kernel_launch(void* const* d_in, const int* in_sizes, int n_in,
                              void* d_out, int out_size, void* d_ws, size_t ws_size,
                              hipStream_t stream) {
    const float* pred = (const float*)d_in[0];
    const float* gt   = (const float*)d_in[1];
    float* out = (float*)d_out;

    double* partials = (double*)d_ws;         // 8 KB, fully overwritten each run

    fused_kernel<<<dim3(NB), dim3(WW), 0, stream>>>(pred, gt, partials, out);
}